// Round 12
// baseline (51.951 us; speedup 1.0000x reference)
//
#include <hip/hip_runtime.h>
#include <hip/hip_bf16.h>

#define B_      4
#define L_      2048
#define NE_     768
#define NOUT_   256     // N_BINS * N_HIDDEN
#define NH_     32
#define NB_     8
#define V_      64
#define VOCAB_  1270
#define NC_     32          // chunks per batch row
#define CS_     64          // L_/NC_
#define BM_     32
#define BK_     64
#define NT_     12          // NE_/BK_
#define NROWS_  8192
#define GRID_MAIN_ 256
#define INV_M_  (1.0f / 4194304.0f) // 1/(B*L*NB*V)
#define INF_    0x7FFFFFFF
#define MAGIC_  0x5F17C3A9u

typedef float f32x4 __attribute__((ext_vector_type(4)));
typedef short s16x8 __attribute__((ext_vector_type(8)));

__device__ __forceinline__ unsigned short f2bf(float x) {
    union { float f; unsigned u; } c; c.f = x;
    unsigned u = c.u;
    return (unsigned short)((u + 0x7fffu + ((u >> 16) & 1u)) >> 16);   // RNE
}
__device__ __forceinline__ unsigned pk2(float lo, float hi) {
    return ((unsigned)f2bf(hi) << 16) | (unsigned)f2bf(lo);
}

// ---------------- workspace layout (bytes) ----------------
// [0     , 32768 ) mt        int[B*L]
// [32768 , 65536 ) firstocc  int[B*NC*V]
// [65536 , 458752) W1t       bf16[256][768]
// [458752, 462848) W2t       bf16[64][32]
// [462848, 463872) partials  float[256]
// [463872, 463876) cnt       unsigned
// [463880, 464008) occflags  unsigned[32]
// [466944, 2564096) tteg     float[B*L*V]

// ---- kernel 1: blocks 0..47 W1t transpose; block 48 W2t + cnt reset;
//      blocks 49..80: mt + firstocc (4 chunks) + release flag;
//      blocks 81..208: tte for one chunk (spins on its batch's 8 flags)
__global__ void __launch_bounds__(256)
k_prep(const int* __restrict__ task_tokens, const float* __restrict__ W1,
       const float* __restrict__ W2, const int* __restrict__ targets,
       const float* __restrict__ age, const float* __restrict__ targets_age,
       short* __restrict__ W1t, short* __restrict__ W2t,
       int* __restrict__ mt, int* __restrict__ firstocc,
       float* __restrict__ tteg, unsigned* __restrict__ cnt,
       unsigned* __restrict__ occflags) {
    __shared__ float tl[64][67];
    __shared__ int   stask[V_];
    __shared__ int   smt[4][CS_];
    __shared__ int   pmin[4][V_];
    __shared__ int   smt2[CS_];
    __shared__ float sage2[CS_];
    const int tid = threadIdx.x;

    if (blockIdx.x < 48) {
        const int tIdx = blockIdx.x;
        const int kt = (tIdx % 12) * 64;
        const int ct = (tIdx / 12) * 64;
        #pragma unroll
        for (int p = 0; p < 4; ++p) {
            int kk = (tid >> 4) + p * 16;
            int cc = (tid & 15) * 4;
            float4 v = *reinterpret_cast<const float4*>(&W1[(kt + kk) * NOUT_ + ct + cc]);
            tl[kk][cc] = v.x; tl[kk][cc + 1] = v.y; tl[kk][cc + 2] = v.z; tl[kk][cc + 3] = v.w;
        }
        __syncthreads();
        #pragma unroll
        for (int p = 0; p < 8; ++p) {
            int oc  = (tid >> 5) + p * 8;
            int ok2 = (tid & 31) * 2;
            unsigned pk = ((unsigned)f2bf(tl[ok2 + 1][oc]) << 16) | f2bf(tl[ok2][oc]);
            *reinterpret_cast<unsigned*>(&W1t[(ct + oc) * NE_ + kt + ok2]) = pk;
        }
        return;
    }
    if (blockIdx.x == 48) {
        if (tid == 0) cnt[0] = 0u;
        #pragma unroll
        for (int q = 0; q < 8; ++q) {
            int i = tid + q * 256;
            int col = i >> 5, j = i & 31;
            W2t[col * NH_ + j] = (short)f2bf(W2[j * V_ + col]);
        }
        return;
    }
    if (blockIdx.x < 81) {
        // ---- occ blocks: 4 chunks each, then release flag ----
        const int u = blockIdx.x - 49;              // 0..31
        if (tid < V_) stask[tid] = task_tokens[tid];
        __syncthreads();
        const int gi = tid >> 6;
        const int v  = tid & 63;
        const int g  = u * 4 + gi;                  // global chunk
        const int b  = g >> 5, c = g & 31;
        int t = targets[b * L_ + c * CS_ + v];
        int mval = -1;
        #pragma unroll
        for (int j = 0; j < V_; ++j)
            mval = (stask[j] == t) ? j : mval;
        mt[b * L_ + c * CS_ + v] = mval;
        smt[gi][v] = mval;                          // wave-local
        int first = INF_;
        for (int j = CS_ - 1; j >= 0; --j)
            if (smt[gi][j] == v) first = c * CS_ + j;
        firstocc[(b * NC_ + c) * V_ + v] = first;
        __syncthreads();
        if (tid == 0)
            __hip_atomic_store(&occflags[u], MAGIC_, __ATOMIC_RELEASE, __HIP_MEMORY_SCOPE_AGENT);
        return;
    }
    // ---- tte blocks: one chunk each ----
    {
        const int g = blockIdx.x - 81;              // 0..127
        const int b = g >> 5, c = g & 31;
        if (tid == 0) {
            const unsigned* f = &occflags[b * 8];
            for (;;) {
                bool ok = true;
                #pragma unroll
                for (int i = 0; i < 8; ++i)
                    ok &= (__hip_atomic_load(&f[i], __ATOMIC_ACQUIRE,
                                             __HIP_MEMORY_SCOPE_AGENT) == MAGIC_);
                if (ok) break;
                __builtin_amdgcn_s_sleep(16);
            }
        }
        __syncthreads();
        const int u2 = tid >> 6;                    // wave 0..3
        const int v2 = tid & 63;
        int cur = INF_;
        #pragma unroll
        for (int k = 0; k < 8; ++k) {
            int cc = c + 1 + u2 + k * 4;
            if (cc < NC_) cur = min(cur, firstocc[(b * NC_ + cc) * V_ + v2]);
        }
        pmin[u2][v2] = cur;
        if (tid < CS_) { smt2[tid] = mt[b * L_ + c * CS_ + tid];
                         sage2[tid] = age[b * L_ + c * CS_ + tid]; }
        __syncthreads();
        int cur2 = min(min(pmin[0][v2], pmin[1][v2]), min(pmin[2][v2], pmin[3][v2]));
        for (int j = CS_ - 1; j >= 0; --j) {
            if (smt2[j] == v2) cur2 = c * CS_ + j;
            if ((j >> 4) == u2) {                   // each wave writes its quarter
                float val = -1.0f;
                if (cur2 != INF_) val = targets_age[b * L_ + cur2] - sage2[j];
                tteg[(b * L_ + c * CS_ + j) * V_ + v2] = val;
            }
        }
    }
}

// ---- kernel 2: depth-3 reg-pipelined bf16 MFMA GEMM1 (BK=64, 12 barriers) +
//                MFMA GEMM2 + loss (tte from global) + last-block final reduce
__global__ void __launch_bounds__(512, 2)
k_main(const float* __restrict__ h, const float* __restrict__ age,
       const float* __restrict__ targets_age,
       const short* __restrict__ W1t, const short* __restrict__ W2t,
       const float* __restrict__ time_bins, const float* __restrict__ tteg,
       float* __restrict__ partials, unsigned* __restrict__ cnt,
       unsigned* __restrict__ occflags, float* __restrict__ out) {
    __shared__ __align__(16) short sA[2][BM_][72];
    __shared__ __align__(16) short sB[2][256][72];  // buf0 reused as sH[8][32][40]
    __shared__ __align__(16) short sW2[V_][40];
    __shared__ float sage[BM_];
    __shared__ float sred[8];
    __shared__ float s2[4];
    __shared__ int   sLast;

    const int tid = threadIdx.x;
    const int w   = tid >> 6;
    const int l   = tid & 63;
    const int l15 = l & 15;
    const int l4  = l >> 4;
    const int kb  = l4 * 8;
    const int r0  = blockIdx.x * BM_;
    const int b   = r0 >> 11;

    // ---- staging geometry ----
    const int arow = tid >> 4;            // 0..31
    const int akc  = (tid & 15) << 2;     // float4 chunk within BK=64
    const int brow = tid >> 1;            // 0..255
    const int bco  = (tid & 1) << 5;      // 32-short half of the 64-wide row
    const float* gA = &h[(r0 + arow) * NE_ + akc];
    const short* gB = &W1t[brow * NE_ + bco];

    // ---- depth-3 slots: issue tiles 0..2 ----
    float4 aS[3];
    s16x8  bS[3][4];
    #pragma unroll
    for (int p = 0; p < 3; ++p) {
        aS[p] = *(const float4*)(gA + p * BK_);
        #pragma unroll
        for (int q = 0; q < 4; ++q)
            bS[p][q] = *(const s16x8*)(gB + p * BK_ + q * 8);
    }

    // ---- small staging (overlaps slot-load latency) ----
    if (tid < BM_) sage[tid] = age[r0 + tid];
    if (tid < 256) {
        int col = tid >> 2, ch = tid & 3;
        *(s16x8*)&sW2[col][ch * 8] = *(const s16x8*)&W2t[col * NH_ + ch * 8];
    }

    // ---- write tile 0 into buf 0 ----
    {
        uint2 pk; pk.x = pk2(aS[0].x, aS[0].y); pk.y = pk2(aS[0].z, aS[0].w);
        *(uint2*)&sA[0][arow][akc] = pk;
        #pragma unroll
        for (int q = 0; q < 4; ++q) *(s16x8*)&sB[0][brow][bco + q * 8] = bS[0][q];
    }
    asm volatile("s_waitcnt lgkmcnt(0)" ::: "memory");
    __builtin_amdgcn_s_barrier();
    asm volatile("" ::: "memory");

    // ---- K loop: 12 iters, 8 MFMA/iter, 1 lgkm-only barrier/iter ----
    f32x4 acc00 = {}, acc01 = {}, acc10 = {}, acc11 = {};
    #pragma unroll
    for (int t = 0; t < NT_; ++t) {
        const int cb = t & 1;
        if (t < NT_ - 1) {                          // write tile t+1 (loaded 2 iters ago)
            const int s = (t + 1) % 3;
            uint2 pk; pk.x = pk2(aS[s].x, aS[s].y); pk.y = pk2(aS[s].z, aS[s].w);
            *(uint2*)&sA[cb ^ 1][arow][akc] = pk;
            #pragma unroll
            for (int q = 0; q < 4; ++q) *(s16x8*)&sB[cb ^ 1][brow][bco + q * 8] = bS[s][q];
        }
        if (t < NT_ - 3) {                          // refill freed slot with tile t+3
            const int s = t % 3;
            aS[s] = *(const float4*)(gA + (t + 3) * BK_);
            #pragma unroll
            for (int q = 0; q < 4; ++q)
                bS[s][q] = *(const s16x8*)(gB + (t + 3) * BK_ + q * 8);
        }
        // k-subtile 0
        s16x8 af00 = *(const s16x8*)&sA[cb][l15][kb];
        s16x8 af10 = *(const s16x8*)&sA[cb][16 + l15][kb];
        s16x8 bf00 = *(const s16x8*)&sB[cb][w * 32 + l15][kb];
        s16x8 bf10 = *(const s16x8*)&sB[cb][w * 32 + 16 + l15][kb];
        acc00 = __builtin_amdgcn_mfma_f32_16x16x32_bf16(af00, bf00, acc00, 0, 0, 0);
        acc01 = __builtin_amdgcn_mfma_f32_16x16x32_bf16(af00, bf10, acc01, 0, 0, 0);
        acc10 = __builtin_amdgcn_mfma_f32_16x16x32_bf16(af10, bf00, acc10, 0, 0, 0);
        acc11 = __builtin_amdgcn_mfma_f32_16x16x32_bf16(af10, bf10, acc11, 0, 0, 0);
        // k-subtile 1
        s16x8 af01 = *(const s16x8*)&sA[cb][l15][32 + kb];
        s16x8 af11 = *(const s16x8*)&sA[cb][16 + l15][32 + kb];
        s16x8 bf01 = *(const s16x8*)&sB[cb][w * 32 + l15][32 + kb];
        s16x8 bf11 = *(const s16x8*)&sB[cb][w * 32 + 16 + l15][32 + kb];
        acc00 = __builtin_amdgcn_mfma_f32_16x16x32_bf16(af01, bf01, acc00, 0, 0, 0);
        acc01 = __builtin_amdgcn_mfma_f32_16x16x32_bf16(af01, bf11, acc01, 0, 0, 0);
        acc10 = __builtin_amdgcn_mfma_f32_16x16x32_bf16(af11, bf01, acc10, 0, 0, 0);
        acc11 = __builtin_amdgcn_mfma_f32_16x16x32_bf16(af11, bf11, acc11, 0, 0, 0);
        asm volatile("s_waitcnt lgkmcnt(0)" ::: "memory");
        __builtin_amdgcn_s_barrier();
        asm volatile("" ::: "memory");
    }
    __syncthreads();

    // ---- hh -> sH (overlaying sB[0]); wave w owns bin n = w ----
    short (*sH)[BM_][40] = (short (*)[BM_][40])&sB[0][0][0];
    #pragma unroll
    for (int jr = 0; jr < 4; ++jr) {
        sH[w][l4 * 4 + jr][l15]           = (short)f2bf(acc00[jr]);
        sH[w][l4 * 4 + jr][16 + l15]      = (short)f2bf(acc01[jr]);
        sH[w][16 + l4 * 4 + jr][l15]      = (short)f2bf(acc10[jr]);
        sH[w][16 + l4 * 4 + jr][16 + l15] = (short)f2bf(acc11[jr]);
    }
    __syncthreads();

    // ---- GEMM2 + loss: wave owns (rf = w&1, cf = w>>1), loops all 8 bins ----
    const int rf = w & 1;
    const int cf = w >> 1;
    const int v  = cf * 16 + l15;
    s16x8 b2 = *(const s16x8*)&sW2[v][l4 * 8];

    float tb[NB_ + 1];
    #pragma unroll
    for (int n = 0; n <= NB_; ++n) tb[n] = time_bins[n];

    float tva[4], lcv[4];
    const float lastTA = targets_age[b * L_ + (L_ - 1)];
    #pragma unroll
    for (int jr = 0; jr < 4; ++jr) {
        int br = rf * 16 + l4 * 4 + jr;
        tva[jr] = tteg[(r0 + br) * V_ + v];
        lcv[jr] = lastTA - sage[br];
    }

    float part = 0.0f;
    const f32x4 zero = {};
    #pragma unroll
    for (int n = 0; n < NB_; ++n) {
        s16x8 a2 = *(const s16x8*)&sH[n][rf * 16 + l15][l4 * 8];
        f32x4 c2 = __builtin_amdgcn_mfma_f32_16x16x32_bf16(a2, b2, zero, 0, 0, 0);
        float sn = tb[n], en = tb[n + 1], wn = en - sn;
        #pragma unroll
        for (int jr = 0; jr < 4; ++jr) {
            float ll = c2[jr];
            float ex = __expf(ll);
            float tv = tva[jr];
            bool occ = (tv > sn) && (tv <= en);
            float cn = fminf(fmaxf(lcv[jr], 0.0f), wn);
            part += ex * (occ ? tv : cn) - (occ ? ll : 0.0f);
        }
    }

    #pragma unroll
    for (int offs = 32; offs > 0; offs >>= 1) part += __shfl_xor(part, offs);
    if (l == 0) sred[w] = part;
    __syncthreads();
    if (tid == 0) {
        float s = 0.0f;
        #pragma unroll
        for (int i = 0; i < 8; ++i) s += sred[i];
        __hip_atomic_store(&partials[blockIdx.x], s, __ATOMIC_RELEASE, __HIP_MEMORY_SCOPE_AGENT);
        unsigned old = __hip_atomic_fetch_add(cnt, 1u, __ATOMIC_ACQ_REL, __HIP_MEMORY_SCOPE_AGENT);
        sLast = (old == GRID_MAIN_ - 1u);
    }
    __syncthreads();
    if (sLast) {
        float x = 0.0f;
        if (tid < 256)
            x = __hip_atomic_load(&partials[tid], __ATOMIC_RELAXED, __HIP_MEMORY_SCOPE_AGENT);
        #pragma unroll
        for (int o = 32; o > 0; o >>= 1) x += __shfl_xor(x, o);
        if (tid < 256 && (tid & 63) == 0) s2[tid >> 6] = x;
        __syncthreads();
        if (tid == 0) out[0] = (s2[0] + s2[1] + s2[2] + s2[3]) * INV_M_;
        if (tid < 32) occflags[tid] = 0u;   // clean flags for the next replay
    }
}

extern "C" void kernel_launch(void* const* d_in, const int* in_sizes, int n_in,
                              void* d_out, int out_size, void* d_ws, size_t ws_size,
                              hipStream_t stream) {
    const float* h           = (const float*)d_in[0];
    const float* age         = (const float*)d_in[1];
    const float* targets_age = (const float*)d_in[2];
    const int*   targets     = (const int*)d_in[3];
    const float* W1          = (const float*)d_in[4];
    const float* W2          = (const float*)d_in[5];
    const int*   task_tokens = (const int*)d_in[6];
    const float* time_bins   = (const float*)d_in[7];
    float* out = (float*)d_out;

    char* ws = (char*)d_ws;
    int*      mt       = (int*)(ws + 0);
    int*      firstocc = (int*)(ws + 32768);
    short*    W1t      = (short*)(ws + 65536);
    short*    W2t      = (short*)(ws + 458752);
    float*    partials = (float*)(ws + 462848);
    unsigned* cnt      = (unsigned*)(ws + 463872);
    unsigned* occflags = (unsigned*)(ws + 463880);
    float*    tteg     = (float*)(ws + 466944);

    hipLaunchKernelGGL(k_prep, dim3(209), dim3(256), 0, stream,
                       task_tokens, W1, W2, targets, age, targets_age,
                       W1t, W2t, mt, firstocc, tteg, cnt, occflags);
    hipLaunchKernelGGL(k_main, dim3(GRID_MAIN_), dim3(512), 0, stream,
                       h, age, targets_age, W1t, W2t, time_bins, tteg,
                       partials, cnt, occflags, out);
}

// Round 13
// 39.916 us; speedup vs baseline: 1.3015x; 1.3015x over previous
//
#include <hip/hip_runtime.h>
#include <hip/hip_bf16.h>

#define B_      4
#define L_      2048
#define NE_     768
#define NOUT_   256     // N_BINS * N_HIDDEN
#define NH_     32
#define NB_     8
#define V_      64
#define VOCAB_  1270
#define NC_     32          // chunks per batch row
#define CS_     64          // L_/NC_
#define BM_     32
#define BK_     32
#define NT_     24          // NE_/BK_
#define NP_     6           // K phases
#define PHI_    4           // iters per phase (KP_/BK_)
#define KP_     128         // K per phase
#define NROWS_  8192
#define GRID_MAIN_ 256
#define INV_M_  (1.0f / 4194304.0f) // 1/(B*L*NB*V)
#define INF_    0x7FFFFFFF

typedef float f32x4 __attribute__((ext_vector_type(4)));
typedef short s16x8 __attribute__((ext_vector_type(8)));

__device__ __forceinline__ unsigned short f2bf(float x) {
    union { float f; unsigned u; } c; c.f = x;
    unsigned u = c.u;
    return (unsigned short)((u + 0x7fffu + ((u >> 16) & 1u)) >> 16);   // RNE
}

__device__ __forceinline__ s16x8 cvt8(float4 a, float4 b) {
    union { __hip_bfloat162 h2[4]; s16x8 v; } r;
    r.h2[0] = __float22bfloat162_rn(make_float2(a.x, a.y));
    r.h2[1] = __float22bfloat162_rn(make_float2(a.z, a.w));
    r.h2[2] = __float22bfloat162_rn(make_float2(b.x, b.y));
    r.h2[3] = __float22bfloat162_rn(make_float2(b.z, b.w));
    return r.v;
}

// ---------------- workspace layout (bytes) ----------------
// [0     , 32768 ) mt        int[B*L]
// [32768 , 65536 ) firstocc  int[B*NC*V]
// [65536 , 458752) W1t       bf16[256][768]
// [458752, 462848) W2t       bf16[64][32]
// [462848, 464896) partials  float[512] (256 used)
// [464896, 464900) cnt       unsigned

// ---- kernel 1: blocks 0..47 W1t transpose; block 48 W2t + cnt reset;
//                blocks 49..80 mt + firstocc (4 chunks per block)
__global__ void __launch_bounds__(256)
k_prep(const int* __restrict__ task_tokens, const float* __restrict__ W1,
       const float* __restrict__ W2, const int* __restrict__ targets,
       short* __restrict__ W1t, short* __restrict__ W2t,
       int* __restrict__ mt, int* __restrict__ firstocc, unsigned* __restrict__ cnt) {
    __shared__ float tl[64][67];
    __shared__ int   stask[V_];
    __shared__ int   smt[4][CS_];
    const int tid = threadIdx.x;

    if (blockIdx.x < 48) {
        const int tIdx = blockIdx.x;
        const int kt = (tIdx % 12) * 64;
        const int ct = (tIdx / 12) * 64;
        #pragma unroll
        for (int p = 0; p < 4; ++p) {
            int kk = (tid >> 4) + p * 16;
            int cc = (tid & 15) * 4;
            float4 v = *reinterpret_cast<const float4*>(&W1[(kt + kk) * NOUT_ + ct + cc]);
            tl[kk][cc] = v.x; tl[kk][cc + 1] = v.y; tl[kk][cc + 2] = v.z; tl[kk][cc + 3] = v.w;
        }
        __syncthreads();
        #pragma unroll
        for (int p = 0; p < 8; ++p) {
            int oc  = (tid >> 5) + p * 8;
            int ok2 = (tid & 31) * 2;
            unsigned pk = ((unsigned)f2bf(tl[ok2 + 1][oc]) << 16) | f2bf(tl[ok2][oc]);
            *reinterpret_cast<unsigned*>(&W1t[(ct + oc) * NE_ + kt + ok2]) = pk;
        }
        return;
    }
    if (blockIdx.x == 48) {
        if (tid == 0) cnt[0] = 0u;
        #pragma unroll
        for (int q = 0; q < 8; ++q) {
            int i = tid + q * 256;
            int col = i >> 5, j = i & 31;
            W2t[col * NH_ + j] = (short)f2bf(W2[j * V_ + col]);
        }
        return;
    }
    // ---- occ blocks: 4 chunks each ----
    if (tid < V_) stask[tid] = task_tokens[tid];
    __syncthreads();
    const int gi = tid >> 6;
    const int v  = tid & 63;
    const int g  = (blockIdx.x - 49) * 4 + gi;
    const int b  = g >> 5, c = g & 31;
    int t = targets[b * L_ + c * CS_ + v];
    int mval = -1;
    #pragma unroll
    for (int j = 0; j < V_; ++j)
        mval = (stask[j] == t) ? j : mval;
    mt[b * L_ + c * CS_ + v] = mval;
    smt[gi][v] = mval;                          // wave-local
    int first = INF_;
    for (int j = CS_ - 1; j >= 0; --j)
        if (smt[gi][j] == v) first = c * CS_ + j;
    firstocc[(b * NC_ + c) * V_ + v] = first;
}

// ---- kernel 2: fused tte + phase-resident-B bf16 MFMA GEMM1(32x256) +
//                MFMA GEMM2 + loss + last-block final reduce
__global__ void __launch_bounds__(512)
k_main(const float* __restrict__ h, const float* __restrict__ age,
       const float* __restrict__ targets_age,
       const int* __restrict__ mt, const int* __restrict__ firstocc,
       const short* __restrict__ W1t, const short* __restrict__ W2t,
       const float* __restrict__ time_bins, float* __restrict__ partials,
       unsigned* __restrict__ cnt, float* __restrict__ out) {
    // double-buffered resident B chunk: 256 cols x 128 k, pad 136 (2-way banks)
    __shared__ __align__(16) short sB[2][256][136];   // 139 KB; sB[0] reused as sH
    __shared__ __align__(16) short sW2[V_][40];
    __shared__ float stte[BM_][66];
    __shared__ int   sminI[8][V_];
    __shared__ int   smt[CS_];
    __shared__ float sage[BM_];
    __shared__ float sred[8];
    __shared__ float s2[4];
    __shared__ int   sLast;

    const int tid = threadIdx.x;
    const int w   = tid >> 6;
    const int l   = tid & 63;
    const int l15 = l & 15;
    const int l4  = l >> 4;
    const int kb  = l4 * 8;
    const int r0  = blockIdx.x * BM_;
    const int b   = r0 >> 11;
    const int pos0 = r0 & (L_ - 1);
    const int c    = pos0 >> 6;           // chunk
    const int off  = pos0 & 63;           // 0 or 32

    // wave split: m = row half (16 rows), n = col quarter (64 cols)
    const int m = w & 1;
    const int n = w >> 1;
    const int bcol = n * 64;

    // ---- A direct-load base (per-wave rows m*16 + l15) ----
    const float* hp = &h[(r0 + m * 16 + l15) * NE_];

    // ---- A slots depth-3: issue tiles 0..2 ----
    float4 x0[3], x1[3];
    #pragma unroll
    for (int p = 0; p < 3; ++p) {
        x0[p] = *(const float4*)&hp[p * BK_ + kb];
        x1[p] = *(const float4*)&hp[p * BK_ + kb + 4];
    }

    // ---- B chunk 0 register prefetch (coalesced: 16 lanes x 16B per row) ----
    s16x8 bpr[8];
    #pragma unroll
    for (int q = 0; q < 8; ++q) {
        int id = tid + q * 512;
        int row = id >> 4, ck = (id & 15) * 8;
        bpr[q] = *(const s16x8*)&W1t[row * NE_ + ck];
    }

    // ---- small staging ----
    if (tid < CS_)  smt[tid]  = mt[b * L_ + c * CS_ + tid];
    if (tid < BM_)  sage[tid] = age[r0 + tid];
    if (tid < 256) {
        int col = tid >> 2, ch = tid & 3;
        *(s16x8*)&sW2[col][ch * 8] = *(const s16x8*)&W2t[col * NH_ + ch * 8];
    }

    // ---- wave-parallel suffix-min over later chunks ----
    {
        int cur = INF_;
        #pragma unroll
        for (int k = 0; k < 4; ++k) {
            int cc = c + 1 + w + k * 8;
            if (cc < NC_) cur = min(cur, firstocc[(b * NC_ + cc) * V_ + l]);
        }
        sminI[w][l] = cur;
    }
    __syncthreads();

    // ---- inline tte scan (wave w owns rows w*4..w*4+3) ----
    {
        const int v  = l;
        const int rg = w;
        int cur = INF_;
        #pragma unroll
        for (int ww = 0; ww < 8; ++ww) cur = min(cur, sminI[ww][v]);
        int* stteI = (int*)stte;
        const int jmin = off + rg * 4;
        for (int j = CS_ - 1; j >= jmin; --j) {
            if (smt[j] == v) cur = c * CS_ + j;
            int br = j - off;
            if ((br >> 2) == rg) stteI[br * 66 + v] = cur;
        }
        #pragma unroll
        for (int jr = 0; jr < 4; ++jr) {
            int br  = rg * 4 + jr;
            int tok = stteI[br * 66 + v];
            float val = -1.0f;
            if (tok != INF_) val = targets_age[b * L_ + tok] - sage[br];
            stte[br][v] = val;
        }
    }

    // ---- write chunk 0 into sB[0], barrier ----
    #pragma unroll
    for (int q = 0; q < 8; ++q) {
        int id = tid + q * 512;
        int row = id >> 4, ck = (id & 15) * 8;
        *(s16x8*)&sB[0][row][ck] = bpr[q];
    }
    asm volatile("s_waitcnt lgkmcnt(0)" ::: "memory");
    __builtin_amdgcn_s_barrier();
    asm volatile("" ::: "memory");

    // ---- prefetch chunk 1 into regs ----
    #pragma unroll
    for (int q = 0; q < 8; ++q) {
        int id = tid + q * 512;
        int row = id >> 4, ck = (id & 15) * 8;
        bpr[q] = *(const s16x8*)&W1t[row * NE_ + KP_ + ck];
    }

    // ---- 6 phases: {write next chunk ∥ issue chunk+2 ∥ 4 barrier-free iters} ----
    f32x4 acc[4] = {};
    #pragma unroll
    for (int p = 0; p < NP_; ++p) {
        if (p < NP_ - 1) {                       // ds_write chunk p+1 -> other buf
            #pragma unroll
            for (int q = 0; q < 8; ++q) {
                int id = tid + q * 512;
                int row = id >> 4, ck = (id & 15) * 8;
                *(s16x8*)&sB[(p + 1) & 1][row][ck] = bpr[q];
            }
        }
        if (p < NP_ - 2) {                       // issue chunk p+2 loads
            #pragma unroll
            for (int q = 0; q < 8; ++q) {
                int id = tid + q * 512;
                int row = id >> 4, ck = (id & 15) * 8;
                bpr[q] = *(const s16x8*)&W1t[row * NE_ + (p + 2) * KP_ + ck];
            }
        }
        #pragma unroll
        for (int ti = 0; ti < PHI_; ++ti) {
            const int t = p * PHI_ + ti;
            const int s = t % 3;
            s16x8 af = cvt8(x0[s], x1[s]);
            if (t + 3 < NT_) {                   // refill slot with tile t+3
                x0[s] = *(const float4*)&hp[(t + 3) * BK_ + kb];
                x1[s] = *(const float4*)&hp[(t + 3) * BK_ + kb + 4];
            }
            __builtin_amdgcn_sched_barrier(0);
            s16x8 bf0 = *(const s16x8*)&sB[p & 1][bcol +      l15][ti * BK_ + kb];
            s16x8 bf1 = *(const s16x8*)&sB[p & 1][bcol + 16 + l15][ti * BK_ + kb];
            s16x8 bf2 = *(const s16x8*)&sB[p & 1][bcol + 32 + l15][ti * BK_ + kb];
            s16x8 bf3 = *(const s16x8*)&sB[p & 1][bcol + 48 + l15][ti * BK_ + kb];
            acc[0] = __builtin_amdgcn_mfma_f32_16x16x32_bf16(af, bf0, acc[0], 0, 0, 0);
            acc[1] = __builtin_amdgcn_mfma_f32_16x16x32_bf16(af, bf1, acc[1], 0, 0, 0);
            acc[2] = __builtin_amdgcn_mfma_f32_16x16x32_bf16(af, bf2, acc[2], 0, 0, 0);
            acc[3] = __builtin_amdgcn_mfma_f32_16x16x32_bf16(af, bf3, acc[3], 0, 0, 0);
        }
        asm volatile("s_waitcnt lgkmcnt(0)" ::: "memory");
        __builtin_amdgcn_s_barrier();
        asm volatile("" ::: "memory");
    }

    // ---- hh -> sH (overlaying sB[0]); wave w: rows m*16.., cols n*64.. ----
    short (*sH)[BM_][40] = (short (*)[BM_][40])&sB[0][0][0];
    #pragma unroll
    for (int cc = 0; cc < 4; ++cc) {
        const int bin = (bcol + cc * 16) >> 5;
        const int jj  = (cc & 1) * 16 + l15;
        #pragma unroll
        for (int jr = 0; jr < 4; ++jr)
            sH[bin][m * 16 + l4 * 4 + jr][jj] = (short)f2bf(acc[cc][jr]);
    }
    __syncthreads();

    // ---- GEMM2 + loss: wave owns (rf = w&1, cf = w>>1), loops all 8 bins ----
    const int rf = w & 1;
    const int cf = w >> 1;
    const int v  = cf * 16 + l15;
    s16x8 b2 = *(const s16x8*)&sW2[v][l4 * 8];

    float tb[NB_ + 1];
    #pragma unroll
    for (int nn = 0; nn <= NB_; ++nn) tb[nn] = time_bins[nn];

    float tva[4], lcv[4];
    const float lastTA = targets_age[b * L_ + (L_ - 1)];
    #pragma unroll
    for (int jr = 0; jr < 4; ++jr) {
        int br = rf * 16 + l4 * 4 + jr;
        tva[jr] = stte[br][v];
        lcv[jr] = lastTA - sage[br];
    }

    float part = 0.0f;
    const f32x4 zero = {};
    #pragma unroll
    for (int nn = 0; nn < NB_; ++nn) {
        s16x8 a2 = *(const s16x8*)&sH[nn][rf * 16 + l15][l4 * 8];
        f32x4 c2 = __builtin_amdgcn_mfma_f32_16x16x32_bf16(a2, b2, zero, 0, 0, 0);
        float sn = tb[nn], en = tb[nn + 1], wn = en - sn;
        #pragma unroll
        for (int jr = 0; jr < 4; ++jr) {
            float ll = c2[jr];
            float ex = __expf(ll);
            float tv = tva[jr];
            bool occ = (tv > sn) && (tv <= en);
            float cn = fminf(fmaxf(lcv[jr], 0.0f), wn);
            part += ex * (occ ? tv : cn) - (occ ? ll : 0.0f);
        }
    }

    #pragma unroll
    for (int offs = 32; offs > 0; offs >>= 1) part += __shfl_xor(part, offs);
    if (l == 0) sred[w] = part;
    __syncthreads();
    if (tid == 0) {
        float s = 0.0f;
        #pragma unroll
        for (int i = 0; i < 8; ++i) s += sred[i];
        __hip_atomic_store(&partials[blockIdx.x], s, __ATOMIC_RELEASE, __HIP_MEMORY_SCOPE_AGENT);
        unsigned old = __hip_atomic_fetch_add(cnt, 1u, __ATOMIC_ACQ_REL, __HIP_MEMORY_SCOPE_AGENT);
        sLast = (old == GRID_MAIN_ - 1u);
    }
    __syncthreads();
    if (sLast) {
        float x = 0.0f;
        if (tid < 256)
            x = __hip_atomic_load(&partials[tid], __ATOMIC_RELAXED, __HIP_MEMORY_SCOPE_AGENT);
        #pragma unroll
        for (int o = 32; o > 0; o >>= 1) x += __shfl_xor(x, o);
        if (tid < 256 && (tid & 63) == 0) s2[tid >> 6] = x;
        __syncthreads();
        if (tid == 0) out[0] = (s2[0] + s2[1] + s2[2] + s2[3]) * INV_M_;
    }
}

extern "C" void kernel_launch(void* const* d_in, const int* in_sizes, int n_in,
                              void* d_out, int out_size, void* d_ws, size_t ws_size,
                              hipStream_t stream) {
    const float* h           = (const float*)d_in[0];
    const float* age         = (const float*)d_in[1];
    const float* targets_age = (const float*)d_in[2];
    const int*   targets     = (const int*)d_in[3];
    const float* W1          = (const float*)d_in[4];
    const float* W2          = (const float*)d_in[5];
    const int*   task_tokens = (const int*)d_in[6];
    const float* time_bins   = (const float*)d_in[7];
    float* out = (float*)d_out;

    char* ws = (char*)d_ws;
    int*      mt       = (int*)(ws + 0);
    int*      firstocc = (int*)(ws + 32768);
    short*    W1t      = (short*)(ws + 65536);
    short*    W2t      = (short*)(ws + 458752);
    float*    partials = (float*)(ws + 462848);
    unsigned* cnt      = (unsigned*)(ws + 464896);

    hipLaunchKernelGGL(k_prep, dim3(81), dim3(256), 0, stream,
                       task_tokens, W1, W2, targets, W1t, W2t, mt, firstocc, cnt);
    hipLaunchKernelGGL(k_main, dim3(GRID_MAIN_), dim3(512), 0, stream,
                       h, age, targets_age, mt, firstocc, W1t, W2t, time_bins,
                       partials, cnt, out);
}

// Round 14
// 35.221 us; speedup vs baseline: 1.4750x; 1.1333x over previous
//
#include <hip/hip_runtime.h>
#include <hip/hip_bf16.h>

#define B_      4
#define L_      2048
#define NE_     768
#define NOUT_   256     // N_BINS * N_HIDDEN
#define NH_     32
#define NB_     8
#define V_      64
#define VOCAB_  1270
#define NC_     32          // chunks per batch row
#define CS_     64          // L_/NC_
#define BM_     32
#define BK_     32
#define NT_     24          // NE_/BK_
#define DEPTH_  4
#define NROWS_  8192
#define GRID_GEMM_ 256
#define GRID_LOSS_ 128
#define INV_M_  (1.0f / 4194304.0f) // 1/(B*L*NB*V)
#define INF_    0x7FFFFFFF

typedef float f32x4 __attribute__((ext_vector_type(4)));
typedef short s16x8 __attribute__((ext_vector_type(8)));

__device__ __forceinline__ unsigned short f2bf(float x) {
    union { float f; unsigned u; } c; c.f = x;
    unsigned u = c.u;
    return (unsigned short)((u + 0x7fffu + ((u >> 16) & 1u)) >> 16);   // RNE
}
__device__ __forceinline__ unsigned pk2(float lo, float hi) {
    return ((unsigned)f2bf(hi) << 16) | (unsigned)f2bf(lo);
}

// ---------------- workspace layout (bytes) ----------------
// [0     , 32768 ) mt        int[B*L]
// [32768 , 65536 ) firstocc  int[B*NC*V]
// [65536 , 458752) W1t       bf16[256][768]
// [458752, 462848) W2t       bf16[64][32]
// [462848, 463360) partials  float[128]
// [463872, 463876) cnt       unsigned
// [466944, 4661248) hhg      bf16[8192][256]

// ---- kernel 1: blocks 0..47 W1t transpose; block 48 W2t + cnt reset;
//                blocks 49..80 mt + firstocc (4 chunks per block)
__global__ void __launch_bounds__(256)
k_prep(const int* __restrict__ task_tokens, const float* __restrict__ W1,
       const float* __restrict__ W2, const int* __restrict__ targets,
       short* __restrict__ W1t, short* __restrict__ W2t,
       int* __restrict__ mt, int* __restrict__ firstocc, unsigned* __restrict__ cnt) {
    __shared__ float tl[64][67];
    __shared__ int   stask[V_];
    __shared__ int   smt[4][CS_];
    const int tid = threadIdx.x;

    if (blockIdx.x < 48) {
        const int tIdx = blockIdx.x;
        const int kt = (tIdx % 12) * 64;
        const int ct = (tIdx / 12) * 64;
        #pragma unroll
        for (int p = 0; p < 4; ++p) {
            int kk = (tid >> 4) + p * 16;
            int cc = (tid & 15) * 4;
            float4 v = *reinterpret_cast<const float4*>(&W1[(kt + kk) * NOUT_ + ct + cc]);
            tl[kk][cc] = v.x; tl[kk][cc + 1] = v.y; tl[kk][cc + 2] = v.z; tl[kk][cc + 3] = v.w;
        }
        __syncthreads();
        #pragma unroll
        for (int p = 0; p < 8; ++p) {
            int oc  = (tid >> 5) + p * 8;
            int ok2 = (tid & 31) * 2;
            unsigned pk = ((unsigned)f2bf(tl[ok2 + 1][oc]) << 16) | f2bf(tl[ok2][oc]);
            *reinterpret_cast<unsigned*>(&W1t[(ct + oc) * NE_ + kt + ok2]) = pk;
        }
        return;
    }
    if (blockIdx.x == 48) {
        if (tid == 0) cnt[0] = 0u;
        #pragma unroll
        for (int q = 0; q < 8; ++q) {
            int i = tid + q * 256;
            int col = i >> 5, j = i & 31;
            W2t[col * NH_ + j] = (short)f2bf(W2[j * V_ + col]);
        }
        return;
    }
    // ---- occ blocks: 4 chunks each ----
    if (tid < V_) stask[tid] = task_tokens[tid];
    __syncthreads();
    const int gi = tid >> 6;
    const int v  = tid & 63;
    const int g  = (blockIdx.x - 49) * 4 + gi;
    const int b  = g >> 5, c = g & 31;
    int t = targets[b * L_ + c * CS_ + v];
    int mval = -1;
    #pragma unroll
    for (int j = 0; j < V_; ++j)
        mval = (stask[j] == t) ? j : mval;
    mt[b * L_ + c * CS_ + v] = mval;
    smt[gi][v] = mval;                          // wave-local
    int first = INF_;
    for (int j = CS_ - 1; j >= 0; --j)
        if (smt[gi][j] == v) first = c * CS_ + j;
    firstocc[(b * NC_ + c) * V_ + v] = first;
}

// ---- kernel 2: PURE GEMM1 (R6's proven depth-4 loop), hh -> global bf16 ----
__global__ void __launch_bounds__(512, 2)
k_gemm(const float* __restrict__ h, const short* __restrict__ W1t,
       short* __restrict__ hhg) {
    __shared__ __align__(16) short sA[2][BM_][40];
    __shared__ __align__(16) short sB[2][256][40];   // sB[0] reused as sH[8][32][40]

    const int tid = threadIdx.x;
    const int w   = tid >> 6;
    const int l   = tid & 63;
    const int l15 = l & 15;
    const int l4  = l >> 4;
    const int r0  = blockIdx.x * BM_;

    const int arow = tid >> 4;
    const int akc  = tid & 15;
    const int brow = tid >> 2;
    const int bch  = tid & 3;
    const float* hA  = &h[(r0 + arow) * NE_ + akc * 2];
    const short* bS0 = &W1t[brow * NE_ + bch * 8];
    const short* bS1 = &W1t[(brow + 128) * NE_ + bch * 8];

    float2 aR[DEPTH_];
    s16x8  bR0[DEPTH_], bR1[DEPTH_];
    #pragma unroll
    for (int p = 0; p < DEPTH_; ++p) {
        aR[p]  = *(const float2*)(hA + p * BK_);
        bR0[p] = *(const s16x8*)(bS0 + p * BK_);
        bR1[p] = *(const s16x8*)(bS1 + p * BK_);
    }
    {
        *(unsigned*)&sA[0][arow][akc * 2] = pk2(aR[0].x, aR[0].y);
        *(s16x8*)&sB[0][brow][bch * 8]       = bR0[0];
        *(s16x8*)&sB[0][brow + 128][bch * 8] = bR1[0];
    }
    asm volatile("s_waitcnt lgkmcnt(0)" ::: "memory");
    __builtin_amdgcn_s_barrier();
    asm volatile("" ::: "memory");

    f32x4 acc[2][2] = {};
    #pragma unroll
    for (int t = 0; t < NT_; ++t) {
        const int cur   = t & 1;
        const int slot  = t & 3;
        const int nslot = (t + 1) & 3;
        if (t < NT_ - DEPTH_) {
            aR[slot]  = *(const float2*)(hA + (t + DEPTH_) * BK_);
            bR0[slot] = *(const s16x8*)(bS0 + (t + DEPTH_) * BK_);
            bR1[slot] = *(const s16x8*)(bS1 + (t + DEPTH_) * BK_);
        }
        s16x8 af0 = *(const s16x8*)&sA[cur][l15][l4 * 8];
        s16x8 af1 = *(const s16x8*)&sA[cur][16 + l15][l4 * 8];
        s16x8 bf0 = *(const s16x8*)&sB[cur][w * 32 + l15][l4 * 8];
        s16x8 bf1 = *(const s16x8*)&sB[cur][w * 32 + 16 + l15][l4 * 8];
        acc[0][0] = __builtin_amdgcn_mfma_f32_16x16x32_bf16(af0, bf0, acc[0][0], 0, 0, 0);
        acc[0][1] = __builtin_amdgcn_mfma_f32_16x16x32_bf16(af0, bf1, acc[0][1], 0, 0, 0);
        acc[1][0] = __builtin_amdgcn_mfma_f32_16x16x32_bf16(af1, bf0, acc[1][0], 0, 0, 0);
        acc[1][1] = __builtin_amdgcn_mfma_f32_16x16x32_bf16(af1, bf1, acc[1][1], 0, 0, 0);
        if (t < NT_ - 1) {
            *(unsigned*)&sA[cur ^ 1][arow][akc * 2] = pk2(aR[nslot].x, aR[nslot].y);
            *(s16x8*)&sB[cur ^ 1][brow][bch * 8]       = bR0[nslot];
            *(s16x8*)&sB[cur ^ 1][brow + 128][bch * 8] = bR1[nslot];
        }
        asm volatile("s_waitcnt lgkmcnt(0)" ::: "memory");
        __builtin_amdgcn_s_barrier();
        asm volatile("" ::: "memory");
    }

    // hh -> sH (overlay sB[0]); wave w owns bin n = w
    short (*sH)[BM_][40] = (short (*)[BM_][40])&sB[0][0][0];
    #pragma unroll
    for (int rf2 = 0; rf2 < 2; ++rf2)
        #pragma unroll
        for (int cfg = 0; cfg < 2; ++cfg) {
            int jj = cfg * 16 + l15;
            #pragma unroll
            for (int jr = 0; jr < 4; ++jr)
                sH[w][rf2 * 16 + l4 * 4 + jr][jj] = (short)f2bf(acc[rf2][cfg][jr]);
        }
    __syncthreads();

    // coalesced store: 16 shorts per thread -> hhg[row][col]
    {
        const int row = tid >> 4;
        const int c8  = (tid & 15) * 16;
        const short* src = &sH[c8 >> 5][row][c8 & 31];
        s16x8 v0 = *(const s16x8*)src;
        s16x8 v1 = *(const s16x8*)(src + 8);
        short* dst = &hhg[(r0 + row) * NOUT_ + c8];
        *(s16x8*)dst       = v0;
        *(s16x8*)(dst + 8) = v1;
    }
}

// ---- kernel 3: tte (once per chunk) + MFMA GEMM2 + loss + last-block reduce
__global__ void __launch_bounds__(512, 2)
k_loss(const float* __restrict__ age, const float* __restrict__ targets_age,
       const int* __restrict__ mt, const int* __restrict__ firstocc,
       const short* __restrict__ hhg, const short* __restrict__ W2t,
       const float* __restrict__ time_bins, float* __restrict__ partials,
       unsigned* __restrict__ cnt, float* __restrict__ out) {
    __shared__ __align__(16) short sW2[V_][40];
    __shared__ float stte[CS_][66];
    __shared__ int   sminI[8][V_];
    __shared__ int   smt[CS_];
    __shared__ float sage[CS_];
    __shared__ float sred[8];
    __shared__ float s2[2];
    __shared__ int   sLast;

    const int tid = threadIdx.x;
    const int w   = tid >> 6;
    const int l   = tid & 63;
    const int l15 = l & 15;
    const int l4  = l >> 4;
    const int g   = blockIdx.x;           // chunk 0..127
    const int b   = g >> 5, c = g & 31;
    const int r0  = g * CS_;

    if (tid < CS_) { smt[tid] = mt[b * L_ + c * CS_ + tid]; sage[tid] = age[r0 + tid]; }
    if (tid < 256) {
        int col = tid >> 2, ch = tid & 3;
        *(s16x8*)&sW2[col][ch * 8] = *(const s16x8*)&W2t[col * NH_ + ch * 8];
    }
    {   // wave-parallel suffix-min over later chunks
        int cur = INF_;
        #pragma unroll
        for (int k = 0; k < 4; ++k) {
            int cc = c + 1 + w + k * 8;
            if (cc < NC_) cur = min(cur, firstocc[(b * NC_ + cc) * V_ + l]);
        }
        sminI[w][l] = cur;
    }
    __syncthreads();
    {   // tte scan: wave rg=w owns rows rg*8..rg*8+7
        const int v = l, rg = w;
        int cur = INF_;
        #pragma unroll
        for (int ww = 0; ww < 8; ++ww) cur = min(cur, sminI[ww][v]);
        int* stteI = (int*)stte;
        const int jmin = rg * 8;
        for (int j = CS_ - 1; j >= jmin; --j) {
            if (smt[j] == v) cur = c * CS_ + j;
            if ((j >> 3) == rg) stteI[j * 66 + v] = cur;
        }
        #pragma unroll
        for (int jr = 0; jr < 8; ++jr) {
            int j = rg * 8 + jr;
            int tok = stteI[j * 66 + v];
            float val = -1.0f;
            if (tok != INF_) val = targets_age[b * L_ + tok] - sage[j];
            stte[j][v] = val;
        }
    }
    __syncthreads();

    // GEMM2 + loss: wave w = bin w; loop rg(4 row-groups) x cf(4 v-groups)
    const float sn = time_bins[w], en = time_bins[w + 1];
    const float wn = en - sn;
    const float lastTA = targets_age[b * L_ + (L_ - 1)];
    float part = 0.0f;
    const f32x4 zero = {};
    #pragma unroll
    for (int rg = 0; rg < 4; ++rg) {
        s16x8 a2 = *(const s16x8*)&hhg[(r0 + rg * 16 + l15) * NOUT_ + w * 32 + l4 * 8];
        float lcv[4];
        #pragma unroll
        for (int jr = 0; jr < 4; ++jr)
            lcv[jr] = lastTA - sage[rg * 16 + l4 * 4 + jr];
        #pragma unroll
        for (int cf = 0; cf < 4; ++cf) {
            int v = cf * 16 + l15;
            s16x8 b2 = *(const s16x8*)&sW2[v][l4 * 8];
            f32x4 c2 = __builtin_amdgcn_mfma_f32_16x16x32_bf16(a2, b2, zero, 0, 0, 0);
            #pragma unroll
            for (int jr = 0; jr < 4; ++jr) {
                int row = rg * 16 + l4 * 4 + jr;
                float ll = c2[jr];
                float ex = __expf(ll);
                float tv = stte[row][v];
                bool occ = (tv > sn) && (tv <= en);
                float cn = fminf(fmaxf(lcv[jr], 0.0f), wn);
                part += ex * (occ ? tv : cn) - (occ ? ll : 0.0f);
            }
        }
    }

    #pragma unroll
    for (int o = 32; o > 0; o >>= 1) part += __shfl_xor(part, o);
    if (l == 0) sred[w] = part;
    __syncthreads();
    if (tid == 0) {
        float s = 0.0f;
        #pragma unroll
        for (int i = 0; i < 8; ++i) s += sred[i];
        __hip_atomic_store(&partials[g], s, __ATOMIC_RELEASE, __HIP_MEMORY_SCOPE_AGENT);
        unsigned old = __hip_atomic_fetch_add(cnt, 1u, __ATOMIC_ACQ_REL, __HIP_MEMORY_SCOPE_AGENT);
        sLast = (old == GRID_LOSS_ - 1u);
    }
    __syncthreads();
    if (sLast) {
        float x = 0.0f;
        if (tid < GRID_LOSS_)
            x = __hip_atomic_load(&partials[tid], __ATOMIC_RELAXED, __HIP_MEMORY_SCOPE_AGENT);
        #pragma unroll
        for (int o = 32; o > 0; o >>= 1) x += __shfl_xor(x, o);
        if (tid < GRID_LOSS_ && l == 0) s2[tid >> 6] = x;
        __syncthreads();
        if (tid == 0) out[0] = (s2[0] + s2[1]) * INV_M_;
    }
}

extern "C" void kernel_launch(void* const* d_in, const int* in_sizes, int n_in,
                              void* d_out, int out_size, void* d_ws, size_t ws_size,
                              hipStream_t stream) {
    const float* h           = (const float*)d_in[0];
    const float* age         = (const float*)d_in[1];
    const float* targets_age = (const float*)d_in[2];
    const int*   targets     = (const int*)d_in[3];
    const float* W1          = (const float*)d_in[4];
    const float* W2          = (const float*)d_in[5];
    const int*   task_tokens = (const int*)d_in[6];
    const float* time_bins   = (const float*)d_in[7];
    float* out = (float*)d_out;

    char* ws = (char*)d_ws;
    int*      mt       = (int*)(ws + 0);
    int*      firstocc = (int*)(ws + 32768);
    short*    W1t      = (short*)(ws + 65536);
    short*    W2t      = (short*)(ws + 458752);
    float*    partials = (float*)(ws + 462848);
    unsigned* cnt      = (unsigned*)(ws + 463872);
    short*    hhg      = (short*)(ws + 466944);

    hipLaunchKernelGGL(k_prep, dim3(81), dim3(256), 0, stream,
                       task_tokens, W1, W2, targets, W1t, W2t, mt, firstocc, cnt);
    hipLaunchKernelGGL(k_gemm, dim3(GRID_GEMM_), dim3(512), 0, stream,
                       h, W1t, hhg);
    hipLaunchKernelGGL(k_loss, dim3(GRID_LOSS_), dim3(512), 0, stream,
                       age, targets_age, mt, firstocc, hhg, W2t, time_bins,
                       partials, cnt, out);
}